// Round 1
// baseline (730.021 us; speedup 1.0000x reference)
//
#include <hip/hip_runtime.h>

#define NPTS 65536
#define WW 1024
#define HWCELLS 65536
#define EPSF 1e-5f

__device__ __forceinline__ float gelu_f(float x) {
    return 0.5f * x * (1.0f + erff(x * 0.70710678118654752440f));
}

__global__ void init_out_k(float* __restrict__ out) {
    int i = blockIdx.x * blockDim.x + threadIdx.x;
    float4* o4 = (float4*)out;
    if (i < 2097152) o4[i] = make_float4(-1.f, -1.f, -1.f, -1.f);
}

__global__ void init_win_k(int* __restrict__ winner) {
    int i = blockIdx.x * blockDim.x + threadIdx.x;
    if (i < HWCELLS) winner[i] = -1;
}

// normalize pc -> xn8 (padded to 8 floats/pt), and record scatter winner (max n per cell)
__global__ void prep_k(const float* __restrict__ pc, const int* __restrict__ px,
                       const int* __restrict__ py,
                       const float* __restrict__ ng, const float* __restrict__ nb,
                       const float* __restrict__ nm, const float* __restrict__ nv,
                       float* __restrict__ xn8, int* __restrict__ winner) {
    int i = blockIdx.x * blockDim.x + threadIdx.x;
    if (i >= NPTS) return;
    float v[5];
#pragma unroll
    for (int c = 0; c < 5; ++c) {
        float s = ng[c] * rsqrtf(nv[c] + EPSF);
        float t = nb[c] - nm[c] * s;
        v[c] = pc[i * 5 + c] * s + t;
    }
    float4* dst = (float4*)&xn8[(size_t)i * 8];
    dst[0] = make_float4(v[0], v[1], v[2], v[3]);
    dst[1] = make_float4(v[4], 0.f, 0.f, 0.f);
    int cell = py[i] * WW + px[i];
    atomicMax(&winner[cell], i);
}

// fold all BN affines + conv1 into compact weight tensors
__global__ void fold_k(const float* __restrict__ w2a,
                       const float* __restrict__ g2a, const float* __restrict__ b2a,
                       const float* __restrict__ m2a, const float* __restrict__ v2a,
                       const float* __restrict__ g2b, const float* __restrict__ b2b,
                       const float* __restrict__ m2b, const float* __restrict__ v2b,
                       const float* __restrict__ w2b,
                       const float* __restrict__ c1w, const float* __restrict__ c1b,
                       const float* __restrict__ fw, const float* __restrict__ fbias,
                       float* __restrict__ w2af, float* __restrict__ b2o,
                       float* __restrict__ w2bt, float* __restrict__ fwnt,
                       float* __restrict__ fw1, float* __restrict__ fbo) {
    int d = threadIdx.x;  // 0..127
    float s2b = g2b[d] * rsqrtf(v2b[d] + EPSF);
    float t2b = b2b[d] - m2b[d] * s2b;
    float acc = 0.f;
#pragma unroll
    for (int c = 0; c < 5; ++c) {
        float s2a = g2a[c] * rsqrtf(v2a[c] + EPSF);
        float t2a = b2a[c] - m2a[c] * s2a;
        float w = w2a[d * 5 + c];
        w2af[d * 8 + c] = s2b * w * s2a;
        acc += w * t2a;
    }
    w2af[d * 8 + 5] = 0.f; w2af[d * 8 + 6] = 0.f; w2af[d * 8 + 7] = 0.f;
    b2o[d] = s2b * acc + t2b;

    // FW1[e][c] = sum_dd final_w[e][dd] * conv1_w[dd][c]; FB[e] = final_b[e] + sum final_w[e][dd]*conv1_b[dd]
    float f1[5] = {0.f, 0.f, 0.f, 0.f, 0.f};
    float accb = fbias[d];
    for (int dd = 0; dd < 128; ++dd) {
        float f = fw[d * 256 + dd];
        accb += f * c1b[dd];
#pragma unroll
        for (int c = 0; c < 5; ++c) f1[c] += f * c1w[dd * 5 + c];
    }
#pragma unroll
    for (int c = 0; c < 5; ++c) fw1[d * 8 + c] = f1[c];
    fw1[d * 8 + 5] = 0.f; fw1[d * 8 + 6] = 0.f; fw1[d * 8 + 7] = 0.f;
    fbo[d] = accb;

    for (int i = 0; i < 128; ++i) w2bt[i * 128 + d] = w2b[d * 128 + i];
    for (int dd = 0; dd < 128; ++dd) fwnt[dd * 128 + d] = fw[d * 256 + 128 + dd];
}

// fused main: per block = 128 points, 512 threads
__launch_bounds__(512, 2)
__global__ void main_k(const int* __restrict__ neighbors,
                       const float* __restrict__ xn8,
                       const int* __restrict__ winner,
                       const int* __restrict__ px, const int* __restrict__ py,
                       const float* __restrict__ w2bt, const float* __restrict__ fwnt,
                       const float* __restrict__ w2af, const float* __restrict__ b2v,
                       const float* __restrict__ fw1, const float* __restrict__ fbv,
                       float* __restrict__ out) {
    __shared__ float wS[128][132];   // w2b^T (later fwnt), stride-132 padded
    __shared__ float gS[128][132];   // g[din][pt] (later m[d][pt])
    __shared__ float xnS[128][8];
    __shared__ float dxS[5][132];
    __shared__ int   nbS[2048];
    __shared__ int   cellS[128];

    const int t = threadIdx.x;
    const int n0 = blockIdx.x * 128;
    const int tc = t & 7;        // dout group: douts tc*16..tc*16+15
    const int tr = t >> 3;       // point pair: pts tr*2, tr*2+1
    const int din_g = t >> 2;    // g-phase: own one din row
    const int p0g = (t & 3) * 32;

    for (int j = t; j < 4096; j += 512) {
        int row = j >> 5;
        int col = (j & 31) << 2;
        *(float4*)&wS[row][col] = *(const float4*)&w2bt[row * 128 + col];
    }
    for (int j = t; j < 2048; j += 512) nbS[j] = neighbors[n0 * 16 + j];
    if (t < 128) {
        int n = n0 + t;
        const float4* src = (const float4*)&xn8[(size_t)n * 8];
        float4 a = src[0];
        float4 b = src[1];
        xnS[t][0] = a.x; xnS[t][1] = a.y; xnS[t][2] = a.z; xnS[t][3] = a.w; xnS[t][4] = b.x;
        int cell = py[n] * WW + px[n];
        cellS[t] = (winner[cell] == n) ? cell : -1;
    }
    float w2ar[5];
    const float b2r = b2v[din_g];
#pragma unroll
    for (int c = 0; c < 5; ++c) w2ar[c] = w2af[din_g * 8 + c];

    float m0[16], m1[16];
#pragma unroll
    for (int jj = 0; jj < 16; ++jj) { m0[jj] = -1e30f; m1[jj] = -1e30f; }

    __syncthreads();

    for (int kk = 0; kk < 15; ++kk) {
        // --- dx phase: 128 threads compute 5-ch neighbor differences ---
        if (t < 128) {
            int nb = nbS[t * 16 + kk + 1];
            const float4* src = (const float4*)&xn8[(size_t)nb * 8];
            float4 a = src[0];
            float4 b = src[1];
            dxS[0][t] = a.x - xnS[t][0];
            dxS[1][t] = a.y - xnS[t][1];
            dxS[2][t] = a.z - xnS[t][2];
            dxS[3][t] = a.w - xnS[t][3];
            dxS[4][t] = b.x - xnS[t][4];
        }
        __syncthreads();
        // --- g phase: g[din][pt] = gelu(W2A'[din]·dx[pt] + B2[din]) ---
        for (int i = 0; i < 32; i += 4) {
            float4 d0 = *(const float4*)&dxS[0][p0g + i];
            float4 d1 = *(const float4*)&dxS[1][p0g + i];
            float4 d2 = *(const float4*)&dxS[2][p0g + i];
            float4 d3 = *(const float4*)&dxS[3][p0g + i];
            float4 d4 = *(const float4*)&dxS[4][p0g + i];
            float4 gv;
            gv.x = gelu_f(b2r + w2ar[0]*d0.x + w2ar[1]*d1.x + w2ar[2]*d2.x + w2ar[3]*d3.x + w2ar[4]*d4.x);
            gv.y = gelu_f(b2r + w2ar[0]*d0.y + w2ar[1]*d1.y + w2ar[2]*d2.y + w2ar[3]*d3.y + w2ar[4]*d4.y);
            gv.z = gelu_f(b2r + w2ar[0]*d0.z + w2ar[1]*d1.z + w2ar[2]*d2.z + w2ar[3]*d3.z + w2ar[4]*d4.z);
            gv.w = gelu_f(b2r + w2ar[0]*d0.w + w2ar[1]*d1.w + w2ar[2]*d2.w + w2ar[3]*d3.w + w2ar[4]*d4.w);
            *(float4*)&gS[din_g][p0g + i] = gv;
        }
        __syncthreads();
        // --- u phase: u[pt][dout] = sum_din g[din][pt] * w2bt[din][dout]; max into m ---
        float u0[16], u1[16];
#pragma unroll
        for (int jj = 0; jj < 16; ++jj) { u0[jj] = 0.f; u1[jj] = 0.f; }
#pragma unroll 4
        for (int din = 0; din < 128; ++din) {
            float2 g2 = *(const float2*)&gS[din][tr * 2];
            const float* wr = &wS[din][tc * 16];
#pragma unroll
            for (int jj = 0; jj < 16; ++jj) {
                float wv = wr[jj];
                u0[jj] = fmaf(g2.x, wv, u0[jj]);
                u1[jj] = fmaf(g2.y, wv, u1[jj]);
            }
        }
#pragma unroll
        for (int jj = 0; jj < 16; ++jj) {
            m0[jj] = fmaxf(m0[jj], u0[jj]);
            m1[jj] = fmaxf(m1[jj], u1[jj]);
        }
        __syncthreads();
    }

    // --- final: feats = FWN^T @ m + FW1·xn + FB; masked scatter-write ---
    for (int j = t; j < 4096; j += 512) {
        int row = j >> 5;
        int col = (j & 31) << 2;
        *(float4*)&wS[row][col] = *(const float4*)&fwnt[row * 128 + col];
    }
#pragma unroll
    for (int jj = 0; jj < 16; ++jj) {
        int d = tc * 16 + jj;
        gS[d][tr * 2]     = m0[jj];
        gS[d][tr * 2 + 1] = m1[jj];
    }
    __syncthreads();

    float f0[16], f1[16];
#pragma unroll
    for (int jj = 0; jj < 16; ++jj) { f0[jj] = 0.f; f1[jj] = 0.f; }
#pragma unroll 4
    for (int din = 0; din < 128; ++din) {
        float2 g2 = *(const float2*)&gS[din][tr * 2];
        const float* wr = &wS[din][tc * 16];
#pragma unroll
        for (int jj = 0; jj < 16; ++jj) {
            float wv = wr[jj];
            f0[jj] = fmaf(g2.x, wv, f0[jj]);
            f1[jj] = fmaf(g2.y, wv, f1[jj]);
        }
    }

    const int pt0 = tr * 2, pt1 = pt0 + 1;
    const int cc0 = cellS[pt0], cc1 = cellS[pt1];
    const float x00 = xnS[pt0][0], x01 = xnS[pt0][1], x02 = xnS[pt0][2], x03 = xnS[pt0][3], x04 = xnS[pt0][4];
    const float x10 = xnS[pt1][0], x11 = xnS[pt1][1], x12 = xnS[pt1][2], x13 = xnS[pt1][3], x14 = xnS[pt1][4];
#pragma unroll
    for (int jj = 0; jj < 16; ++jj) {
        int e = tc * 16 + jj;
        float base = fbv[e];
        const float* w1 = &fw1[e * 8];
        float r0 = base + w1[0]*x00 + w1[1]*x01 + w1[2]*x02 + w1[3]*x03 + w1[4]*x04 + f0[jj];
        float r1 = base + w1[0]*x10 + w1[1]*x11 + w1[2]*x12 + w1[3]*x13 + w1[4]*x14 + f1[jj];
        if (cc0 >= 0) out[e * HWCELLS + cc0] = r0;
        if (cc1 >= 0) out[e * HWCELLS + cc1] = r1;
    }
}

extern "C" void kernel_launch(void* const* d_in, const int* in_sizes, int n_in,
                              void* d_out, int out_size, void* d_ws, size_t ws_size,
                              hipStream_t stream) {
    const float* pc        = (const float*)d_in[0];
    const int*   neighbors = (const int*)d_in[1];
    const int*   px        = (const int*)d_in[2];
    const int*   py        = (const int*)d_in[3];
    const float* norm_g    = (const float*)d_in[4];
    const float* norm_b    = (const float*)d_in[5];
    const float* norm_m    = (const float*)d_in[6];
    const float* norm_v    = (const float*)d_in[7];
    const float* conv1_w   = (const float*)d_in[8];
    const float* conv1_b   = (const float*)d_in[9];
    const float* bn2a_g    = (const float*)d_in[10];
    const float* bn2a_b    = (const float*)d_in[11];
    const float* bn2a_m    = (const float*)d_in[12];
    const float* bn2a_v    = (const float*)d_in[13];
    const float* w2a       = (const float*)d_in[14];
    const float* bn2b_g    = (const float*)d_in[15];
    const float* bn2b_b    = (const float*)d_in[16];
    const float* bn2b_m    = (const float*)d_in[17];
    const float* bn2b_v    = (const float*)d_in[18];
    const float* w2b       = (const float*)d_in[19];
    const float* final_w   = (const float*)d_in[20];
    const float* final_b   = (const float*)d_in[21];
    float* out = (float*)d_out;

    char* ws = (char*)d_ws;
    float* xn8   = (float*)(ws);                 // 524288 floats (2 MB)
    int*   winner= (int*)(ws + 2097152);         // 65536 ints
    float* w2bt  = (float*)(ws + 2359296);       // 16384 floats
    float* fwnt  = (float*)(ws + 2424832);       // 16384 floats
    float* w2af  = (float*)(ws + 2490368);       // 1024 floats
    float* b2    = (float*)(ws + 2494464);       // 128 floats
    float* fw1   = (float*)(ws + 2494976);       // 1024 floats
    float* fb    = (float*)(ws + 2499072);       // 128 floats

    init_out_k<<<8192, 256, 0, stream>>>(out);
    init_win_k<<<256, 256, 0, stream>>>(winner);
    prep_k<<<256, 256, 0, stream>>>(pc, px, py, norm_g, norm_b, norm_m, norm_v, xn8, winner);
    fold_k<<<1, 128, 0, stream>>>(w2a, bn2a_g, bn2a_b, bn2a_m, bn2a_v,
                                  bn2b_g, bn2b_b, bn2b_m, bn2b_v, w2b,
                                  conv1_w, conv1_b, final_w, final_b,
                                  w2af, b2, w2bt, fwnt, fw1, fb);
    main_k<<<512, 512, 0, stream>>>(neighbors, xn8, winner, px, py,
                                    w2bt, fwnt, w2af, b2, fw1, fb, out);
}

// Round 2
// 165.819 us; speedup vs baseline: 4.4025x; 4.4025x over previous
//
#include <hip/hip_runtime.h>

#define NPTS 65536
#define WW 1024
#define HWCELLS 65536
#define EPSF 1e-5f
#define QPTS 32

typedef __attribute__((ext_vector_type(8))) short short8;
typedef __attribute__((ext_vector_type(4))) float f32x4;

__device__ __forceinline__ float gelu_f(float x) {
    return 0.5f * x * (1.0f + erff(x * 0.70710678118654752440f));
}
__device__ __forceinline__ unsigned f2bf_rne(float x) {
    unsigned u = __float_as_uint(x);
    return (u + 0x7fffu + ((u >> 16) & 1u)) >> 16;
}
__device__ __forceinline__ unsigned pk2(float lo, float hi) {
    return f2bf_rne(lo) | (f2bf_rne(hi) << 16);
}
__device__ __forceinline__ float bflo(unsigned u) { return __uint_as_float(u << 16); }
__device__ __forceinline__ float bfhi(unsigned u) { return __uint_as_float(u & 0xffff0000u); }

__global__ void init_out_k(float* __restrict__ out) {
    int i = blockIdx.x * blockDim.x + threadIdx.x;
    float4* o4 = (float4*)out;
    if (i < 2097152) o4[i] = make_float4(-1.f, -1.f, -1.f, -1.f);
}

__global__ void init_win_k(int* __restrict__ winner) {
    int i = blockIdx.x * blockDim.x + threadIdx.x;
    if (i < HWCELLS) winner[i] = -1;
}

__global__ void prep_k(const float* __restrict__ pc, const int* __restrict__ px,
                       const int* __restrict__ py,
                       const float* __restrict__ ng, const float* __restrict__ nb,
                       const float* __restrict__ nm, const float* __restrict__ nv,
                       float* __restrict__ xn8, int* __restrict__ winner) {
    int i = blockIdx.x * blockDim.x + threadIdx.x;
    if (i >= NPTS) return;
    float v[5];
#pragma unroll
    for (int c = 0; c < 5; ++c) {
        float s = ng[c] * rsqrtf(nv[c] + EPSF);
        float t = nb[c] - nm[c] * s;
        v[c] = pc[i * 5 + c] * s + t;
    }
    float4* dst = (float4*)&xn8[(size_t)i * 8];
    dst[0] = make_float4(v[0], v[1], v[2], v[3]);
    dst[1] = make_float4(v[4], 0.f, 0.f, 0.f);
    int cell = py[i] * WW + px[i];
    atomicMax(&winner[cell], i);
}

// fold BN affines; emit: w2af8 [128][8] f32, b2 [128] f32,
// w2bB [128][128] bf16 (row-major, A-operand), fwallB [128][160] bf16
// (cols 0..127 = final_w[:,128:256], 128..132 = final_w[:,0:128]@conv1_w,
//  133 = final_b + final_w[:,0:128]@conv1_b, 134..159 = 0)
__global__ void fold_k(const float* __restrict__ w2a,
                       const float* __restrict__ g2a, const float* __restrict__ b2a,
                       const float* __restrict__ m2a, const float* __restrict__ v2a,
                       const float* __restrict__ g2b, const float* __restrict__ b2b,
                       const float* __restrict__ m2b, const float* __restrict__ v2b,
                       const float* __restrict__ w2b,
                       const float* __restrict__ c1w, const float* __restrict__ c1b,
                       const float* __restrict__ fw, const float* __restrict__ fbias,
                       float* __restrict__ w2af8, float* __restrict__ b2o,
                       unsigned short* __restrict__ w2bB,
                       unsigned short* __restrict__ fwallB) {
    int d = threadIdx.x;  // 0..127
    float s2b = g2b[d] * rsqrtf(v2b[d] + EPSF);
    float t2b = b2b[d] - m2b[d] * s2b;
    float acc = 0.f;
#pragma unroll
    for (int c = 0; c < 5; ++c) {
        float s2a = g2a[c] * rsqrtf(v2a[c] + EPSF);
        float t2a = b2a[c] - m2a[c] * s2a;
        float wv = w2a[d * 5 + c];
        w2af8[d * 8 + c] = s2b * wv * s2a;
        acc += s2b * wv * t2a;
    }
    w2af8[d * 8 + 5] = 0.f; w2af8[d * 8 + 6] = 0.f; w2af8[d * 8 + 7] = 0.f;
    b2o[d] = acc + t2b;

    for (int i = 0; i < 128; ++i)
        w2bB[d * 128 + i] = (unsigned short)f2bf_rne(w2b[d * 128 + i]);

    for (int j = 0; j < 128; ++j)
        fwallB[d * 160 + j] = (unsigned short)f2bf_rne(fw[d * 256 + 128 + j]);
    float f1[5] = {0.f, 0.f, 0.f, 0.f, 0.f};
    float fbv = fbias[d];
    for (int dd = 0; dd < 128; ++dd) {
        float f = fw[d * 256 + dd];
        fbv += f * c1b[dd];
#pragma unroll
        for (int c = 0; c < 5; ++c) f1[c] += f * c1w[dd * 5 + c];
    }
#pragma unroll
    for (int c = 0; c < 5; ++c)
        fwallB[d * 160 + 128 + c] = (unsigned short)f2bf_rne(f1[c]);
    fwallB[d * 160 + 133] = (unsigned short)f2bf_rne(fbv);
    for (int j = 134; j < 160; ++j) fwallB[d * 160 + j] = 0;
}

// Y[n][din] bf16 = W2A' @ xn[n]  (no bias)
__global__ void y_k(const float* __restrict__ xn8, const float* __restrict__ w2af8,
                    unsigned short* __restrict__ Y) {
    __shared__ float wS[1024];
    int t = threadIdx.x;
    for (int j = t; j < 1024; j += 256) wS[j] = w2af8[j];
    __syncthreads();
    int n = blockIdx.x * 256 + t;
    const float4 xa = *(const float4*)&xn8[(size_t)n * 8];
    const float x4 = xn8[(size_t)n * 8 + 4];
    unsigned* Yo = (unsigned*)(Y + (size_t)n * 128);
#pragma unroll
    for (int blk = 0; blk < 16; ++blk) {
        unsigned p[4];
#pragma unroll
        for (int q = 0; q < 4; ++q) {
            int d = blk * 8 + q * 2;
            const float* wr = &wS[d * 8];
            float a = wr[0]*xa.x + wr[1]*xa.y + wr[2]*xa.z + wr[3]*xa.w + wr[4]*x4;
            const float* wr2 = &wS[(d + 1) * 8];
            float b = wr2[0]*xa.x + wr2[1]*xa.y + wr2[2]*xa.z + wr2[3]*xa.w + wr2[4]*x4;
            p[q] = pk2(a, b);
        }
        uint4 u; u.x = p[0]; u.y = p[1]; u.z = p[2]; u.w = p[3];
        *(uint4*)&Yo[blk * 4] = u;
    }
}

// fused MFMA main: 32 points / block, 256 threads (4 waves)
__launch_bounds__(256, 3)
__global__ void main_k(const int* __restrict__ nbrs,
                       const float* __restrict__ xn8,
                       const int* __restrict__ winner,
                       const int* __restrict__ px, const int* __restrict__ py,
                       const unsigned short* __restrict__ Y,
                       const float* __restrict__ b2,
                       const unsigned short* __restrict__ w2bB,
                       const unsigned short* __restrict__ fwallB,
                       float* __restrict__ out) {
    __shared__ unsigned short Gsh[2][QPTS * 128];  // [buf][pt*128 + din], XOR-swizzled
    __shared__ unsigned short Msh[QPTS * 160];     // [pt*160 + k], swizzled for k<128
    __shared__ int   nbS[QPTS * 16];
    __shared__ float xnS[QPTS][8];
    __shared__ int   cellS[QPTS];

    const int t = threadIdx.x;
    const int w = t >> 6;     // wave 0..3 -> dout rows w*32..w*32+31
    const int l = t & 63;
    const int n0 = blockIdx.x * QPTS;
    const int l15 = l & 15;
    const int lg  = l >> 4;   // k-group 0..3

    // stage per-block data
    for (int j = t; j < QPTS * 16; j += 256) nbS[j] = nbrs[n0 * 16 + j];
    if (t < QPTS) {
        int n = n0 + t;
        float4 a = *(const float4*)&xn8[(size_t)n * 8];
        float b = xn8[(size_t)n * 8 + 4];
        xnS[t][0] = a.x; xnS[t][1] = a.y; xnS[t][2] = a.z; xnS[t][3] = a.w;
        xnS[t][4] = b;   xnS[t][5] = 0.f; xnS[t][6] = 0.f; xnS[t][7] = 0.f;
        int cell = py[n] * WW + px[n];
        cellS[t] = (winner[cell] == n) ? cell : -1;
    }

    // A fragments: w2b rows [w*32, w*32+32), all K=128
    short8 afrag[2][4];
#pragma unroll
    for (int rt = 0; rt < 2; ++rt)
#pragma unroll
        for (int ks = 0; ks < 4; ++ks) {
            int row = w * 32 + rt * 16 + l15;
            int k0 = ks * 32 + lg * 8;
            afrag[rt][ks] = *(const short8*)(w2bB + row * 128 + k0);
        }

    // g-producer role: dins dinblk*4..+3, pts ptblk*4..+3
    const int dinblk = t & 31;
    const int ptblk  = t >> 5;
    const float4 b2q = *(const float4*)&b2[dinblk * 4];
    float c0a[4][4];
#pragma unroll
    for (int i = 0; i < 4; ++i) {
        int n = n0 + ptblk * 4 + i;
        uint2 yp = *(const uint2*)(Y + (size_t)n * 128 + dinblk * 4);
        c0a[i][0] = b2q.x - bflo(yp.x);
        c0a[i][1] = b2q.y - bfhi(yp.x);
        c0a[i][2] = b2q.z - bflo(yp.y);
        c0a[i][3] = b2q.w - bfhi(yp.y);
    }

    __syncthreads();  // nbS ready

    uint2 ycur[4], ynxt[4];
#pragma unroll
    for (int i = 0; i < 4; ++i) {
        int nb = nbS[(ptblk * 4 + i) * 16 + 1];
        ycur[i] = *(const uint2*)(Y + (size_t)nb * 128 + dinblk * 4);
    }

    f32x4 acc[2][2];
    f32x4 mmax[2][2];
#pragma unroll
    for (int rt = 0; rt < 2; ++rt)
#pragma unroll
        for (int ct = 0; ct < 2; ++ct)
#pragma unroll
            for (int j = 0; j < 4; ++j) { acc[rt][ct][j] = 0.f; mmax[rt][ct][j] = -1e30f; }

    const int swzw = (ptblk * 4 & 15) << 4;  // base; per-pt below

    for (int kk = 0; kk < 15; ++kk) {
        // prefetch Y[nb] for next kk
        if (kk < 14) {
#pragma unroll
            for (int i = 0; i < 4; ++i) {
                int nb = nbS[(ptblk * 4 + i) * 16 + kk + 2];
                ynxt[i] = *(const uint2*)(Y + (size_t)nb * 128 + dinblk * 4);
            }
        }
        // gelu -> G[kk&1]
        {
            char* Gb = (char*)Gsh[kk & 1];
#pragma unroll
            for (int i = 0; i < 4; ++i) {
                int pt = ptblk * 4 + i;
                float g0 = gelu_f(bflo(ycur[i].x) + c0a[i][0]);
                float g1 = gelu_f(bfhi(ycur[i].x) + c0a[i][1]);
                float g2 = gelu_f(bflo(ycur[i].y) + c0a[i][2]);
                float g3 = gelu_f(bfhi(ycur[i].y) + c0a[i][3]);
                uint2 pr; pr.x = pk2(g0, g1); pr.y = pk2(g2, g3);
                *(uint2*)(Gb + pt * 256 + ((dinblk * 8) ^ ((pt & 15) << 4))) = pr;
            }
        }
        __syncthreads();
        // MFMA on G[kk&1]
        {
            const char* Gr = (const char*)Gsh[kk & 1];
#pragma unroll
            for (int ks = 0; ks < 4; ++ks) {
                short8 bfrag[2];
#pragma unroll
                for (int ct = 0; ct < 2; ++ct) {
                    int pt = ct * 16 + l15;
                    int kb = (ks * 32 + lg * 8) * 2;
                    bfrag[ct] = *(const short8*)(Gr + pt * 256 + (kb ^ ((pt & 15) << 4)));
                }
#pragma unroll
                for (int rt = 0; rt < 2; ++rt)
#pragma unroll
                    for (int ct = 0; ct < 2; ++ct)
                        acc[rt][ct] = __builtin_amdgcn_mfma_f32_16x16x32_bf16(
                            afrag[rt][ks], bfrag[ct], acc[rt][ct], 0, 0, 0);
            }
#pragma unroll
            for (int rt = 0; rt < 2; ++rt)
#pragma unroll
                for (int ct = 0; ct < 2; ++ct)
#pragma unroll
                    for (int j = 0; j < 4; ++j) {
                        mmax[rt][ct][j] = fmaxf(mmax[rt][ct][j], acc[rt][ct][j]);
                        acc[rt][ct][j] = 0.f;
                    }
        }
        if (kk < 14) {
#pragma unroll
            for (int i = 0; i < 4; ++i) ycur[i] = ynxt[i];
        }
    }
    (void)swzw;

    // write running max -> Msh as B-operand [pt][k=dout] bf16 (k<128 swizzled)
    {
        char* Mb = (char*)Msh;
#pragma unroll
        for (int rt = 0; rt < 2; ++rt)
#pragma unroll
            for (int ct = 0; ct < 2; ++ct) {
                int pt = ct * 16 + l15;
                int dout = w * 32 + rt * 16 + lg * 4;
                unsigned lo = pk2(mmax[rt][ct][0], mmax[rt][ct][1]);
                unsigned hi = pk2(mmax[rt][ct][2], mmax[rt][ct][3]);
                int sw = (pt & 15) << 4;
                *(unsigned*)(Mb + pt * 320 + ((dout * 2) ^ sw)) = lo;
                *(unsigned*)(Mb + pt * 320 + (((dout + 2) * 2) ^ sw)) = hi;
            }
        if (t < QPTS) {
            unsigned v0 = pk2(xnS[t][0], xnS[t][1]);
            unsigned v1 = pk2(xnS[t][2], xnS[t][3]);
            unsigned v2 = pk2(xnS[t][4], 1.0f);
            uint4 a; a.x = v0; a.y = v1; a.z = v2; a.w = 0u;
            uint4 z; z.x = 0u; z.y = 0u; z.z = 0u; z.w = 0u;
            *(uint4*)(Mb + t * 320 + 256) = a;
            *(uint4*)(Mb + t * 320 + 272) = z;
            *(uint4*)(Mb + t * 320 + 288) = z;
            *(uint4*)(Mb + t * 320 + 304) = z;
        }
    }
    __syncthreads();

    // final GEMM: feats[e][pt] = fwallB(128x160) @ M(160xQPTS)
    f32x4 facc[2][2];
#pragma unroll
    for (int rt = 0; rt < 2; ++rt)
#pragma unroll
        for (int ct = 0; ct < 2; ++ct)
#pragma unroll
            for (int j = 0; j < 4; ++j) facc[rt][ct][j] = 0.f;

    const char* Mr = (const char*)Msh;
#pragma unroll
    for (int ks = 0; ks < 5; ++ks) {
        short8 af[2], bfr[2];
#pragma unroll
        for (int rt = 0; rt < 2; ++rt) {
            int row = w * 32 + rt * 16 + l15;
            af[rt] = *(const short8*)(fwallB + row * 160 + ks * 32 + lg * 8);
        }
#pragma unroll
        for (int ct = 0; ct < 2; ++ct) {
            int pt = ct * 16 + l15;
            int kb = (ks * 32 + lg * 8) * 2;
            int kbs = (kb < 256) ? (kb ^ ((pt & 15) << 4)) : kb;
            bfr[ct] = *(const short8*)(Mr + pt * 320 + kbs);
        }
#pragma unroll
        for (int rt = 0; rt < 2; ++rt)
#pragma unroll
            for (int ct = 0; ct < 2; ++ct)
                facc[rt][ct] = __builtin_amdgcn_mfma_f32_16x16x32_bf16(
                    af[rt], bfr[ct], facc[rt][ct], 0, 0, 0);
    }

    // masked scatter: winner points only
#pragma unroll
    for (int ct = 0; ct < 2; ++ct) {
        int cell = cellS[ct * 16 + l15];
        if (cell >= 0) {
#pragma unroll
            for (int rt = 0; rt < 2; ++rt) {
                int ebase = w * 32 + rt * 16 + lg * 4;
#pragma unroll
                for (int j = 0; j < 4; ++j)
                    out[(size_t)(ebase + j) * HWCELLS + cell] = facc[rt][ct][j];
            }
        }
    }
}

extern "C" void kernel_launch(void* const* d_in, const int* in_sizes, int n_in,
                              void* d_out, int out_size, void* d_ws, size_t ws_size,
                              hipStream_t stream) {
    const float* pc        = (const float*)d_in[0];
    const int*   neighbors = (const int*)d_in[1];
    const int*   px        = (const int*)d_in[2];
    const int*   py        = (const int*)d_in[3];
    const float* norm_g    = (const float*)d_in[4];
    const float* norm_b    = (const float*)d_in[5];
    const float* norm_m    = (const float*)d_in[6];
    const float* norm_v    = (const float*)d_in[7];
    const float* conv1_w   = (const float*)d_in[8];
    const float* conv1_b   = (const float*)d_in[9];
    const float* bn2a_g    = (const float*)d_in[10];
    const float* bn2a_b    = (const float*)d_in[11];
    const float* bn2a_m    = (const float*)d_in[12];
    const float* bn2a_v    = (const float*)d_in[13];
    const float* w2a       = (const float*)d_in[14];
    const float* bn2b_g    = (const float*)d_in[15];
    const float* bn2b_b    = (const float*)d_in[16];
    const float* bn2b_m    = (const float*)d_in[17];
    const float* bn2b_v    = (const float*)d_in[18];
    const float* w2b       = (const float*)d_in[19];
    const float* final_w   = (const float*)d_in[20];
    const float* final_b   = (const float*)d_in[21];
    float* out = (float*)d_out;

    char* ws = (char*)d_ws;
    float*          xn8    = (float*)(ws);                       // 2,097,152 B
    int*            winner = (int*)(ws + 2097152);               //   262,144 B
    unsigned short* Y      = (unsigned short*)(ws + 2359296);    // 16,777,216 B
    float*          w2af8  = (float*)(ws + 19136512);            //     4,096 B
    float*          b2     = (float*)(ws + 19140608);            //       512 B
    unsigned short* w2bB   = (unsigned short*)(ws + 19141120);   //    32,768 B
    unsigned short* fwallB = (unsigned short*)(ws + 19173888);   //    40,960 B

    init_out_k<<<8192, 256, 0, stream>>>(out);
    init_win_k<<<256, 256, 0, stream>>>(winner);
    prep_k<<<256, 256, 0, stream>>>(pc, px, py, norm_g, norm_b, norm_m, norm_v, xn8, winner);
    fold_k<<<1, 128, 0, stream>>>(w2a, bn2a_g, bn2a_b, bn2a_m, bn2a_v,
                                  bn2b_g, bn2b_b, bn2b_m, bn2b_v, w2b,
                                  conv1_w, conv1_b, final_w, final_b,
                                  w2af8, b2, w2bB, fwallB);
    y_k<<<256, 256, 0, stream>>>(xn8, w2af8, Y);
    main_k<<<2048, 256, 0, stream>>>(neighbors, xn8, winner, px, py,
                                     Y, b2, w2bB, fwallB, out);
}